// Round 2
// baseline (311.600 us; speedup 1.0000x reference)
//
#include <hip/hip_runtime.h>
#include <math.h>

// Problem constants
#define BATCH 32
#define H 512
#define W 512
#define OUTD 502          // 512 - 11 + 1
#define WS 11
#define STRIP 32          // output rows per block
#define INROWS 42         // STRIP + WS - 1 input rows per strip
#define BW 266            // LDS row width: 256 cols + 10 halo

#define C1F 6.5025f       // (0.01*255)^2
#define C2F 58.5225f      // (0.03*255)^2
#define N_OUT_TOTAL 8064128.0   // 32 * 502 * 502

struct GW { float g[WS]; };
struct H5 { float v[5]; };

// Streaming SSIM: one thread per output column, 32-row strip per block.
// Per input row: global RGB -> luma -> LDS row (double-buffered, 1 barrier/row)
// -> 11-tap horizontal conv (registers) -> 11-deep rolling vertical
// accumulator ring (registers). SSIM emitted on completion of each output row.
__global__ __launch_bounds__(256, 4) void ssim_stream_kernel(
    const float* __restrict__ img1, const float* __restrict__ img2,
    double* __restrict__ acc_out, GW wv)
{
    __shared__ float bufA[2][BW];
    __shared__ float bufB[2][BW];
    __shared__ double wsum[4];

    const int t  = threadIdx.x;
    const int bx = blockIdx.x;          // column block: 0 -> cols 0..255, 1 -> 256..501
    const int by = blockIdx.y;          // row strip
    const int b  = blockIdx.z;          // batch

    const int c0   = bx * 256;          // thread t loads input col c0+t
    const int ox   = c0 + t;            // output column owned by this thread
    const int r0   = by * STRIP;        // first input row (== first output row) of strip
    const bool colok = (ox < OUTD);

    const size_t imgbase = (size_t)b * H * W * 3;

    // Load luma for (strip row iy, cols c0+t and c0+256+t). Zero outside range.
    auto load_luma = [&](int iy, float& la, float& lb, float& la2, float& lb2) {
        la = lb = la2 = lb2 = 0.f;
        const int r = r0 + iy;
        if (iy < INROWS && r < H) {
            const size_t rowb = imgbase + (size_t)r * (W * 3);
            {
                const size_t p = rowb + (size_t)(c0 + t) * 3;
                float r1 = img1[p], g1 = img1[p + 1], b1 = img1[p + 2];
                float r2 = img2[p], g2 = img2[p + 1], b2 = img2[p + 2];
                r1 = (r1 + 1.f) * 127.5f; g1 = (g1 + 1.f) * 127.5f; b1 = (b1 + 1.f) * 127.5f;
                r2 = (r2 + 1.f) * 127.5f; g2 = (g2 + 1.f) * 127.5f; b2 = (b2 + 1.f) * 127.5f;
                la = (r1 * 65.738f + g1 * 129.057f + b1 * 25.064f) * (1.f / 256.f) + 16.f;
                lb = (r2 * 65.738f + g2 * 129.057f + b2 * 25.064f) * (1.f / 256.f) + 16.f;
            }
            if (t < 10 && (c0 + 256 + t) < W) {
                const size_t p = rowb + (size_t)(c0 + 256 + t) * 3;
                float r1 = img1[p], g1 = img1[p + 1], b1 = img1[p + 2];
                float r2 = img2[p], g2 = img2[p + 1], b2 = img2[p + 2];
                r1 = (r1 + 1.f) * 127.5f; g1 = (g1 + 1.f) * 127.5f; b1 = (b1 + 1.f) * 127.5f;
                r2 = (r2 + 1.f) * 127.5f; g2 = (g2 + 1.f) * 127.5f; b2 = (b2 + 1.f) * 127.5f;
                la2 = (r1 * 65.738f + g1 * 129.057f + b1 * 25.064f) * (1.f / 256.f) + 16.f;
                lb2 = (r2 * 65.738f + g2 * 129.057f + b2 * 25.064f) * (1.f / 256.f) + 16.f;
            }
        }
    };

    // Pending row (iy+1) luma held in registers between iterations.
    float rlA, rlB, rlA2, rlB2;

    // Preloop: row 0 -> buf[0]; row 1 -> registers (in flight).
    {
        float a, bv, a2, b2;
        load_luma(0, a, bv, a2, b2);
        load_luma(1, rlA, rlB, rlA2, rlB2);
        bufA[0][t] = a; bufB[0][t] = bv;
        if (t < 10) { bufA[0][256 + t] = a2; bufB[0][256 + t] = b2; }
    }

    // One row step: prefetch row iy+2, barrier, store row iy+1, h-conv row iy.
    auto row_step = [&](int iy) -> H5 {
        float nA, nB, nA2, nB2;
        load_luma(iy + 2, nA, nB, nA2, nB2);
        __syncthreads();
        {
            const int wb = (iy + 1) & 1;
            bufA[wb][t] = rlA; bufB[wb][t] = rlB;
            if (t < 10) { bufA[wb][256 + t] = rlA2; bufB[wb][256 + t] = rlB2; }
        }
        rlA = nA; rlB = nB; rlA2 = nA2; rlB2 = nB2;
        const float* __restrict__ ra = bufA[iy & 1];
        const float* __restrict__ rb = bufB[iy & 1];
        float h0 = 0.f, h1 = 0.f, h2 = 0.f, h3 = 0.f, h4 = 0.f;
        #pragma unroll
        for (int k = 0; k < WS; ++k) {
            const float gk = wv.g[k];
            const float a = ra[t + k];
            const float c = rb[t + k];
            h0 += gk * a;
            h1 += gk * c;
            h2 += gk * a * a;
            h3 += gk * c * c;
            h4 += gk * a * c;
        }
        H5 h; h.v[0] = h0; h.v[1] = h1; h.v[2] = h2; h.v[3] = h3; h.v[4] = h4;
        return h;
    };

    double local = 0.0;
    auto complete = [&](const float* a, int oy) {
        if (colok && (r0 + oy) < OUTD) {
            const float mu1 = a[0], mu2 = a[1];
            const float mu1s = mu1 * mu1, mu2s = mu2 * mu2, mu12 = mu1 * mu2;
            const float num = (2.f * mu12 + C1F) * (2.f * (a[4] - mu12) + C2F);
            const float den = (mu1s + mu2s + C1F) * ((a[2] - mu1s) + (a[3] - mu2s) + C2F);
            local += (double)(num / den);
        }
    };

    // Rolling accumulator ring: slot s holds output row oy with oy % 11 == s.
    float acc[WS][5];
    #pragma unroll
    for (int s = 0; s < WS; ++s)
        #pragma unroll
        for (int ch = 0; ch < 5; ++ch) acc[s][ch] = 0.f;

    // ---- Chunk 0: iy = 0..10 (only taps with oy = iy-k >= 0) ----
    #pragma unroll
    for (int j = 0; j < 11; ++j) {
        H5 h = row_step(j);
        #pragma unroll
        for (int k = 0; k < WS; ++k) {
            if (k <= j) {                       // static: oy = j-k >= 0
                const float gk = wv.g[k];
                #pragma unroll
                for (int ch = 0; ch < 5; ++ch) acc[j - k][ch] += gk * h.v[ch];
            }
        }
    }
    complete(acc[0], 0);                        // oy=0 done after iy=10
    #pragma unroll
    for (int ch = 0; ch < 5; ++ch) acc[0][ch] = 0.f;

    // ---- Chunks 1..2: iy = 11c+j, full 11 taps; completes oy = iy-10 ----
    for (int c = 1; c <= 2; ++c) {
        const int iy0 = c * 11;
        #pragma unroll
        for (int j = 0; j < 11; ++j) {
            H5 h = row_step(iy0 + j);
            #pragma unroll
            for (int k = 0; k < WS; ++k) {
                const float gk = wv.g[k];
                const int s = (j - k + 11) % 11;    // static slot
                #pragma unroll
                for (int ch = 0; ch < 5; ++ch) acc[s][ch] += gk * h.v[ch];
            }
            const int sc = (j + 1) % 11;
            complete(acc[sc], iy0 + j - 10);
            #pragma unroll
            for (int ch = 0; ch < 5; ++ch) acc[sc][ch] = 0.f;
        }
    }

    // ---- Chunk 3 (tail): iy = 33..41; only taps reaching oy <= 31 ----
    #pragma unroll
    for (int j = 0; j < 9; ++j) {
        H5 h = row_step(33 + j);
        #pragma unroll
        for (int k = 0; k < WS; ++k) {
            if (k >= j + 2) {                   // static: oy = 33+j-k <= 31
                const float gk = wv.g[k];
                const int s = (j - k + 22) % 11;
                #pragma unroll
                for (int ch = 0; ch < 5; ++ch) acc[s][ch] += gk * h.v[ch];
            }
        }
        const int sc = (j + 1) % 11;
        complete(acc[sc], 23 + j);
        #pragma unroll
        for (int ch = 0; ch < 5; ++ch) acc[sc][ch] = 0.f;
    }

    // ---- Block reduction: wave shuffle -> LDS -> one atomic ----
    for (int off = 32; off > 0; off >>= 1)
        local += __shfl_down(local, off, 64);
    const int lane = t & 63;
    const int wvid = t >> 6;
    if (lane == 0) wsum[wvid] = local;
    __syncthreads();
    if (t == 0) {
        const double s = wsum[0] + wsum[1] + wsum[2] + wsum[3];
        atomicAdd(acc_out, s);
    }
}

__global__ void ssim_finalize_kernel(const double* __restrict__ acc,
                                     float* __restrict__ out)
{
    out[0] = (float)(acc[0] / N_OUT_TOTAL);
}

extern "C" void kernel_launch(void* const* d_in, const int* in_sizes, int n_in,
                              void* d_out, int out_size, void* d_ws, size_t ws_size,
                              hipStream_t stream) {
    const float* img1 = (const float*)d_in[0];
    const float* img2 = (const float*)d_in[1];
    float* out = (float*)d_out;
    double* acc = (double*)d_ws;

    // Gaussian window, computed exactly as the numpy reference (float32 ops)
    GW w;
    {
        float g[WS];
        float s = 0.f;
        for (int i = 0; i < WS; ++i) {
            const float x = (float)(i - WS / 2);
            g[i] = expf(-(x * x) / (2.f * 1.5f * 1.5f));
            s += g[i];
        }
        for (int i = 0; i < WS; ++i) w.g[i] = g[i] / s;
    }

    hipMemsetAsync(d_ws, 0, sizeof(double), stream);

    dim3 grid(2, (OUTD + STRIP - 1) / STRIP, BATCH);   // 2 x 16 x 32 = 1024 blocks
    ssim_stream_kernel<<<grid, 256, 0, stream>>>(img1, img2, acc, w);
    ssim_finalize_kernel<<<1, 1, 0, stream>>>(acc, out);
}

// Round 3
// 275.041 us; speedup vs baseline: 1.1329x; 1.1329x over previous
//
#include <hip/hip_runtime.h>
#include <math.h>

// Problem constants
#define BATCH 32
#define H 512
#define W 512
#define OUTD 502          // 512 - 11 + 1
#define WS 11
#define STRIP 32          // output rows per block
#define INROWS 42         // STRIP + WS - 1 input rows per strip
#define BW 266            // LDS row width: 256 cols + 10 halo

#define C1F 6.5025f       // (0.01*255)^2
#define C2F 58.5225f      // (0.03*255)^2
#define N_OUT_TOTAL 8064128.0   // 32 * 502 * 502

struct GW { float g[WS]; };

__device__ __forceinline__ float luma3(float r, float g, float b) {
    r = (r + 1.f) * 127.5f; g = (g + 1.f) * 127.5f; b = (b + 1.f) * 127.5f;
    return (r * 65.738f + g * 129.057f + b * 25.064f) * (1.f / 256.f) + 16.f;
}

// Streaming SSIM, one thread per output column, 32-row strip per block.
// Per input row: global RGB -> luma -> double-buffered LDS row -> 11-tap
// horizontal conv (4 channels: a, b, a^2+b^2, a*b) -> 11-deep register ring
// -> vertical conv + SSIM the moment an output row's 11th input row lands.
// All ring indices are compile-time (%11 folds under full unroll); no
// pointers into register arrays (round-2 spill lesson: WRITE_SIZE 136MB).
__global__ __launch_bounds__(256) void ssim_stream_kernel(
    const float* __restrict__ img1, const float* __restrict__ img2,
    double* __restrict__ acc_out, GW wv)
{
    __shared__ float bufA[2][BW];
    __shared__ float bufB[2][BW];
    __shared__ double wsum[4];

    const int t  = threadIdx.x;
    const int bx = blockIdx.x;          // 0 -> cols 0..255, 1 -> 256..501
    const int by = blockIdx.y;          // row strip
    const int b  = blockIdx.z;          // batch

    const int c0 = bx * 256;
    const int ox = c0 + t;              // output column owned by this thread
    const int r0 = by * STRIP;
    const bool colok = (ox < OUTD);
    const bool halo  = (t < 10) && ((c0 + 256 + t) < W);
    const size_t imgbase = (size_t)b * (H * W * 3);
    const size_t colA = (size_t)(c0 + t) * 3;
    const size_t colB = (size_t)(c0 + 256 + t) * 3;

    float rlA, rlB, rlA2, rlB2;         // pending luma for row iy+1
    float nA, nB, nA2, nB2;             // prefetched luma for row iy+2

#define LOAD_LUMA(IY, LA, LB, LA2, LB2)                                   \
    {                                                                     \
        LA = LB = LA2 = LB2 = 0.f;                                        \
        const int _r = r0 + (IY);                                         \
        if ((IY) < INROWS && _r < H) {                                    \
            const size_t _rowb = imgbase + (size_t)_r * (W * 3);          \
            {                                                             \
                const float* _p1 = img1 + _rowb + colA;                   \
                const float* _p2 = img2 + _rowb + colA;                   \
                LA = luma3(_p1[0], _p1[1], _p1[2]);                       \
                LB = luma3(_p2[0], _p2[1], _p2[2]);                       \
            }                                                             \
            if (halo) {                                                   \
                const float* _p1 = img1 + _rowb + colB;                   \
                const float* _p2 = img2 + _rowb + colB;                   \
                LA2 = luma3(_p1[0], _p1[1], _p1[2]);                      \
                LB2 = luma3(_p2[0], _p2[1], _p2[2]);                      \
            }                                                             \
        }                                                                 \
    }

    // Register ring: slot s holds h-conv of input row r with r % 11 == s.
    float rm1[WS], rm2[WS], rq[WS], rx[WS];

    // Preloop: row 0 -> buf[0]; row 1 -> registers (in flight).
    {
        float a0, b0, a02, b02;
        LOAD_LUMA(0, a0, b0, a02, b02);
        LOAD_LUMA(1, rlA, rlB, rlA2, rlB2);
        bufA[0][t] = a0; bufB[0][t] = b0;
        if (t < 10) { bufA[0][256 + t] = a02; bufB[0][256 + t] = b02; }
    }

// One row step: prefetch luma(iy+2); barrier; store luma(iy+1) to LDS;
// horizontal 11-tap conv of row iy from LDS into H0..H3.
#define ROW_STEP(IY, H0, H1, H2, H3)                                      \
    {                                                                     \
        LOAD_LUMA((IY) + 2, nA, nB, nA2, nB2);                            \
        __syncthreads();                                                  \
        {                                                                 \
            const int _wb = ((IY) + 1) & 1;                               \
            bufA[_wb][t] = rlA; bufB[_wb][t] = rlB;                       \
            if (t < 10) { bufA[_wb][256 + t] = rlA2;                      \
                          bufB[_wb][256 + t] = rlB2; }                    \
        }                                                                 \
        rlA = nA; rlB = nB; rlA2 = nA2; rlB2 = nB2;                       \
        {                                                                 \
            const int _rbidx = (IY) & 1;                                  \
            float _h0 = 0.f, _h1 = 0.f, _h2 = 0.f, _h3 = 0.f;             \
            _Pragma("unroll")                                             \
            for (int _k = 0; _k < WS; ++_k) {                             \
                const float _gk = wv.g[_k];                               \
                const float _a = bufA[_rbidx][t + _k];                    \
                const float _c = bufB[_rbidx][t + _k];                    \
                _h0 += _gk * _a;                                          \
                _h1 += _gk * _c;                                          \
                _h2 += _gk * (_a * _a + _c * _c);                         \
                _h3 += _gk * (_a * _c);                                   \
            }                                                             \
            H0 = _h0; H1 = _h1; H2 = _h2; H3 = _h3;                       \
        }                                                                 \
    }

    // Fill ring with input rows 0..9 (slots 0..9).
    #pragma unroll
    for (int j = 0; j < 10; ++j)
        ROW_STEP(j, rm1[j], rm2[j], rq[j], rx[j]);

    double local = 0.0;

// Output row OY (JM == OY % 11, compile-time): insert row OY+10 at slot
// (JM+10)%11, then vertical 11-tap conv over slots (JM+k)%11 and SSIM.
#define DO_ROW(OY, JM)                                                    \
    {                                                                     \
        ROW_STEP((OY) + 10,                                               \
                 rm1[((JM) + 10) % WS], rm2[((JM) + 10) % WS],            \
                 rq[((JM) + 10) % WS],  rx[((JM) + 10) % WS]);            \
        float _mu1 = 0.f, _mu2 = 0.f, _eq = 0.f, _ex = 0.f;               \
        _Pragma("unroll")                                                 \
        for (int _k = 0; _k < WS; ++_k) {                                 \
            const float _gk = wv.g[_k];                                   \
            const int _s = ((JM) + _k) % WS;                              \
            _mu1 += _gk * rm1[_s];                                        \
            _mu2 += _gk * rm2[_s];                                        \
            _eq  += _gk * rq[_s];                                         \
            _ex  += _gk * rx[_s];                                         \
        }                                                                 \
        if (colok && (r0 + (OY)) < OUTD) {                                \
            const float _m1s = _mu1 * _mu1;                               \
            const float _m2s = _mu2 * _mu2;                               \
            const float _m12 = _mu1 * _mu2;                               \
            const float _num = (2.f * _m12 + C1F) *                       \
                               (2.f * (_ex - _m12) + C2F);                \
            const float _den = (_m1s + _m2s + C1F) *                      \
                               ((_eq - _m1s - _m2s) + C2F);               \
            local += (double)(_num / _den);                               \
        }                                                                 \
    }

    // Output rows 0..21 in two groups of 11 (base % 11 == 0 keeps slots
    // static); tail rows 22..31.
    for (int c = 0; c < 2; ++c) {
        const int base = c * 11;
        #pragma unroll
        for (int j = 0; j < 11; ++j)
            DO_ROW(base + j, j);
    }
    #pragma unroll
    for (int j = 0; j < 10; ++j)
        DO_ROW(22 + j, j);

    // Block reduction: wave shuffle -> LDS -> one atomic.
    for (int off = 32; off > 0; off >>= 1)
        local += __shfl_down(local, off, 64);
    const int lane = t & 63;
    const int wvid = t >> 6;
    if (lane == 0) wsum[wvid] = local;
    __syncthreads();
    if (t == 0) {
        const double s = wsum[0] + wsum[1] + wsum[2] + wsum[3];
        atomicAdd(acc_out, s);
    }
}

__global__ void ssim_finalize_kernel(const double* __restrict__ acc,
                                     float* __restrict__ out)
{
    out[0] = (float)(acc[0] / N_OUT_TOTAL);
}

extern "C" void kernel_launch(void* const* d_in, const int* in_sizes, int n_in,
                              void* d_out, int out_size, void* d_ws, size_t ws_size,
                              hipStream_t stream) {
    const float* img1 = (const float*)d_in[0];
    const float* img2 = (const float*)d_in[1];
    float* out = (float*)d_out;
    double* acc = (double*)d_ws;

    // Gaussian window, computed exactly as the numpy reference (float32 ops)
    GW w;
    {
        float g[WS];
        float s = 0.f;
        for (int i = 0; i < WS; ++i) {
            const float x = (float)(i - WS / 2);
            g[i] = expf(-(x * x) / (2.f * 1.5f * 1.5f));
            s += g[i];
        }
        for (int i = 0; i < WS; ++i) w.g[i] = g[i] / s;
    }

    hipMemsetAsync(d_ws, 0, sizeof(double), stream);

    dim3 grid(2, (OUTD + STRIP - 1) / STRIP, BATCH);   // 2 x 16 x 32 = 1024 blocks
    ssim_stream_kernel<<<grid, 256, 0, stream>>>(img1, img2, acc, w);
    ssim_finalize_kernel<<<1, 1, 0, stream>>>(acc, out);
}

// Round 4
// 267.568 us; speedup vs baseline: 1.1646x; 1.0279x over previous
//
#include <hip/hip_runtime.h>
#include <math.h>

// Problem constants
#define BATCH 32
#define H 512
#define W 512
#define OUTD 502          // 512 - 11 + 1
#define WS 11
#define STRIP 32          // output rows per block
#define INROWS 42         // STRIP + WS - 1 input rows per strip
#define WPAD 80           // per-wave LDS row width: 64 cols + 10 halo + pad

#define C1F 6.5025f       // (0.01*255)^2
#define C2F 58.5225f      // (0.03*255)^2
#define N_OUT_TOTAL 8064128.0   // 32 * 502 * 502

struct GW { float g[WS]; };

__device__ __forceinline__ float luma3(float r, float g, float b) {
    r = (r + 1.f) * 127.5f; g = (g + 1.f) * 127.5f; b = (b + 1.f) * 127.5f;
    return (r * 65.738f + g * 129.057f + b * 25.064f) * (1.f / 256.f) + 16.f;
}

// Streaming SSIM, one thread per output column, 32-row strip per block.
// WAVE-PRIVATE LDS: each of the block's 4 waves owns 64 output columns and
// its own 74-wide double-buffered luma rows, so the row loop needs ZERO
// __syncthreads (round-3 lesson: 42 barriers/block made the kernel
// latency-bound at VALUBusy 35%). Within a wave, DS ops are in-order and
// the compiler inserts lgkmcnt waits -> write/read of wave-private LDS is
// safe without barriers.
// Per input row: global RGB -> luma (prefetched one row ahead in registers)
// -> wave-private LDS row -> 11-tap horizontal conv (4 channels: a, b,
// a^2+b^2, a*b) -> 11-deep register ring -> vertical conv + SSIM as soon as
// an output row's 11th input row lands. Ring indices are compile-time
// (%11 folds under full unroll); no pointers into register arrays
// (round-2 spill lesson: WRITE_SIZE 136MB).
__global__ __launch_bounds__(256) void ssim_stream_kernel(
    const float* __restrict__ img1, const float* __restrict__ img2,
    double* __restrict__ acc_out, GW wv)
{
    __shared__ float sbuf[2][4][2][WPAD];   // parity x wave x img x width = 5120 B
    __shared__ double wsum[4];

    const int t    = threadIdx.x;
    const int lane = t & 63;
    const int wvid = t >> 6;
    const int cw = blockIdx.x * 256 + wvid * 64;  // wave's first column
    const int ox = cw + lane;                     // owned output column (<= 511)
    const int r0 = blockIdx.y * STRIP;
    const int b  = blockIdx.z;

    const bool colok = (ox < OUTD);
    const bool halo  = (lane < 10) && ((cw + 64 + lane) < W);
    const size_t imgbase = (size_t)b * (H * W * 3);
    const size_t colA = (size_t)(cw + lane) * 3;        // main col, always < W
    const size_t colB = (size_t)(cw + 64 + lane) * 3;   // halo col

    float rlA, rlB, rlA2, rlB2;         // pending luma for row iy+1
    float nA, nB, nA2, nB2;             // prefetched luma for row iy+2

#define LOAD_LUMA(IY, LA, LB, LA2, LB2)                                   \
    {                                                                     \
        LA = LB = LA2 = LB2 = 0.f;                                        \
        const int _r = r0 + (IY);                                         \
        if ((IY) < INROWS && _r < H) {                                    \
            const size_t _rowb = imgbase + (size_t)_r * (W * 3);          \
            {                                                             \
                const float* _p1 = img1 + _rowb + colA;                   \
                const float* _p2 = img2 + _rowb + colA;                   \
                LA = luma3(_p1[0], _p1[1], _p1[2]);                       \
                LB = luma3(_p2[0], _p2[1], _p2[2]);                       \
            }                                                             \
            if (halo) {                                                   \
                const float* _p1 = img1 + _rowb + colB;                   \
                const float* _p2 = img2 + _rowb + colB;                   \
                LA2 = luma3(_p1[0], _p1[1], _p1[2]);                      \
                LB2 = luma3(_p2[0], _p2[1], _p2[2]);                      \
            }                                                             \
        }                                                                 \
    }

    // Register ring: slot s holds h-conv of input row r with r % 11 == s.
    float rm1[WS], rm2[WS], rq[WS], rx[WS];

    // Preloop: row 0 -> buf[0]; row 1 -> registers (in flight).
    {
        float a0, b0, a02, b02;
        LOAD_LUMA(0, a0, b0, a02, b02);
        LOAD_LUMA(1, rlA, rlB, rlA2, rlB2);
        sbuf[0][wvid][0][lane] = a0;
        sbuf[0][wvid][1][lane] = b0;
        if (lane < 10) {
            sbuf[0][wvid][0][64 + lane] = a02;
            sbuf[0][wvid][1][64 + lane] = b02;
        }
    }

// One row step: prefetch luma(iy+2); store luma(iy+1) to the other parity;
// horizontal 11-tap conv of row iy from wave-private LDS into H0..H3.
// NO barrier: buffers are wave-private.
#define ROW_STEP(IY, H0, H1, H2, H3)                                      \
    {                                                                     \
        LOAD_LUMA((IY) + 2, nA, nB, nA2, nB2);                            \
        {                                                                 \
            const int _wb = ((IY) + 1) & 1;                               \
            sbuf[_wb][wvid][0][lane] = rlA;                               \
            sbuf[_wb][wvid][1][lane] = rlB;                               \
            if (lane < 10) {                                              \
                sbuf[_wb][wvid][0][64 + lane] = rlA2;                     \
                sbuf[_wb][wvid][1][64 + lane] = rlB2;                     \
            }                                                             \
        }                                                                 \
        rlA = nA; rlB = nB; rlA2 = nA2; rlB2 = nB2;                       \
        {                                                                 \
            const int _rb = (IY) & 1;                                     \
            float _h0 = 0.f, _h1 = 0.f, _h2 = 0.f, _h3 = 0.f;             \
            _Pragma("unroll")                                             \
            for (int _k = 0; _k < WS; ++_k) {                             \
                const float _gk = wv.g[_k];                               \
                const float _a = sbuf[_rb][wvid][0][lane + _k];           \
                const float _c = sbuf[_rb][wvid][1][lane + _k];           \
                _h0 += _gk * _a;                                          \
                _h1 += _gk * _c;                                          \
                _h2 += _gk * (_a * _a + _c * _c);                         \
                _h3 += _gk * (_a * _c);                                   \
            }                                                             \
            H0 = _h0; H1 = _h1; H2 = _h2; H3 = _h3;                       \
        }                                                                 \
    }

    // Fill ring with input rows 0..9 (slots 0..9).
    #pragma unroll
    for (int j = 0; j < 10; ++j)
        ROW_STEP(j, rm1[j], rm2[j], rq[j], rx[j]);

    double local = 0.0;

// Output row OY (JM == OY % 11, compile-time): insert row OY+10 at slot
// (JM+10)%11, then vertical 11-tap conv over slots (JM+k)%11 and SSIM.
#define DO_ROW(OY, JM)                                                    \
    {                                                                     \
        ROW_STEP((OY) + 10,                                               \
                 rm1[((JM) + 10) % WS], rm2[((JM) + 10) % WS],            \
                 rq[((JM) + 10) % WS],  rx[((JM) + 10) % WS]);            \
        float _mu1 = 0.f, _mu2 = 0.f, _eq = 0.f, _ex = 0.f;               \
        _Pragma("unroll")                                                 \
        for (int _k = 0; _k < WS; ++_k) {                                 \
            const float _gk = wv.g[_k];                                   \
            const int _s = ((JM) + _k) % WS;                              \
            _mu1 += _gk * rm1[_s];                                        \
            _mu2 += _gk * rm2[_s];                                        \
            _eq  += _gk * rq[_s];                                         \
            _ex  += _gk * rx[_s];                                         \
        }                                                                 \
        if (colok && (r0 + (OY)) < OUTD) {                                \
            const float _m1s = _mu1 * _mu1;                               \
            const float _m2s = _mu2 * _mu2;                               \
            const float _m12 = _mu1 * _mu2;                               \
            const float _num = (2.f * _m12 + C1F) *                       \
                               (2.f * (_ex - _m12) + C2F);                \
            const float _den = (_m1s + _m2s + C1F) *                      \
                               ((_eq - _m1s - _m2s) + C2F);               \
            local += (double)(_num / _den);                               \
        }                                                                 \
    }

    // Output rows 0..21 in two groups of 11 (base % 11 == 0 keeps slots
    // static); tail rows 22..31.
    for (int c = 0; c < 2; ++c) {
        const int base = c * 11;
        #pragma unroll
        for (int j = 0; j < 11; ++j)
            DO_ROW(base + j, j);
    }
    #pragma unroll
    for (int j = 0; j < 10; ++j)
        DO_ROW(22 + j, j);

    // Block reduction: wave shuffle -> LDS -> one atomic (only barrier).
    for (int off = 32; off > 0; off >>= 1)
        local += __shfl_down(local, off, 64);
    if (lane == 0) wsum[wvid] = local;
    __syncthreads();
    if (t == 0) {
        const double s = wsum[0] + wsum[1] + wsum[2] + wsum[3];
        atomicAdd(acc_out, s);
    }
}

__global__ void ssim_finalize_kernel(const double* __restrict__ acc,
                                     float* __restrict__ out)
{
    out[0] = (float)(acc[0] / N_OUT_TOTAL);
}

extern "C" void kernel_launch(void* const* d_in, const int* in_sizes, int n_in,
                              void* d_out, int out_size, void* d_ws, size_t ws_size,
                              hipStream_t stream) {
    const float* img1 = (const float*)d_in[0];
    const float* img2 = (const float*)d_in[1];
    float* out = (float*)d_out;
    double* acc = (double*)d_ws;

    // Gaussian window, computed exactly as the numpy reference (float32 ops)
    GW w;
    {
        float g[WS];
        float s = 0.f;
        for (int i = 0; i < WS; ++i) {
            const float x = (float)(i - WS / 2);
            g[i] = expf(-(x * x) / (2.f * 1.5f * 1.5f));
            s += g[i];
        }
        for (int i = 0; i < WS; ++i) w.g[i] = g[i] / s;
    }

    hipMemsetAsync(d_ws, 0, sizeof(double), stream);

    dim3 grid(2, (OUTD + STRIP - 1) / STRIP, BATCH);   // 2 x 16 x 32 = 1024 blocks
    ssim_stream_kernel<<<grid, 256, 0, stream>>>(img1, img2, acc, w);
    ssim_finalize_kernel<<<1, 1, 0, stream>>>(acc, out);
}

// Round 5
// 259.053 us; speedup vs baseline: 1.2028x; 1.0329x over previous
//
#include <hip/hip_runtime.h>
#include <math.h>

// Problem constants
#define BATCH 32
#define H 512
#define W 512
#define OUTD 502          // 512 - 11 + 1
#define WS 11
#define STRIP 32          // output rows per block
#define INROWS 42         // STRIP + WS - 1 input rows per strip
#define WPAD 80           // per-wave LDS row width: 64 cols + 10 halo + pad

#define C1F 6.5025f       // (0.01*255)^2
#define C2F 58.5225f      // (0.03*255)^2
#define N_OUT_TOTAL 8064128.0   // 32 * 502 * 502

struct GW { float g[WS]; };

__device__ __forceinline__ float luma3(float r, float g, float b) {
    r = (r + 1.f) * 127.5f; g = (g + 1.f) * 127.5f; b = (b + 1.f) * 127.5f;
    return (r * 65.738f + g * 129.057f + b * 25.064f) * (1.f / 256.f) + 16.f;
}

// Streaming SSIM, one thread per output column, 32-row strip per block,
// wave-private LDS (no barriers in the row loop — round-4).
// ROUND-5 FIX: raw RGB global loads are software-pipelined one full row
// ahead of their first USE (round-4 bug: loads were consumed by luma3 in
// the same macro -> per-row vmcnt stall, VALUBusy 37%). Step iy:
//   1. issue raw loads for row iy+2 (no use)
//   2. luma-convert raw row iy+1 (loaded last step) -> wave-private LDS
//   3. 11-tap horizontal conv of row iy from LDS (4 ch: a, b, a^2+b^2, ab)
//   4. 11-deep register ring -> vertical conv + SSIM when a row completes
// Ring indices compile-time (%11 folds under unroll); no pointers into
// register arrays (round-2 spill: WRITE_SIZE 136MB). FP math order is
// bit-identical to round 4 (absmax margin only 27%).
__global__ __launch_bounds__(256) void ssim_stream_kernel(
    const float* __restrict__ img1, const float* __restrict__ img2,
    double* __restrict__ acc_out, GW wv)
{
    __shared__ float sbuf[2][4][2][WPAD];   // parity x wave x img x width
    __shared__ double wsum[4];

    const int t    = threadIdx.x;
    const int lane = t & 63;
    const int wvid = t >> 6;
    const int cw = blockIdx.x * 256 + wvid * 64;  // wave's first column
    const int ox = cw + lane;                     // owned output column
    const int r0 = blockIdx.y * STRIP;
    const int b  = blockIdx.z;

    const bool colok = (ox < OUTD);
    const bool halo  = (lane < 10) && ((cw + 64 + lane) < W);
    const size_t imgbase = (size_t)b * (H * W * 3) + (size_t)r0 * (W * 3);
    const int colA = (cw + lane) * 3;             // main col (always < W)
    const int colB = (cw + 64 + lane) * 3;        // halo col

    // Raw RGB pipeline registers: c* = row iy+1 (ready), n* = row iy+2 (in flight)
    float cA0, cA1, cA2, cB0, cB1, cB2, cC0, cC1, cC2, cD0, cD1, cD2;
    float nA0, nA1, nA2, nB0, nB1, nB2, nC0, nC1, nC2, nD0, nD1, nD2;

// Issue raw loads for strip row IY into 12 named registers (NO conversion
// here — keeping load->use distance at one full row step).
#define LOAD_RAW(IY, A0,A1,A2, B0,B1,B2, C0,C1v,C2v, D0,D1,D2)            \
    {                                                                     \
        A0=A1=A2=B0=B1=B2=C0=C1v=C2v=D0=D1=D2 = 0.f;                      \
        if ((IY) < INROWS && (r0 + (IY)) < H) {                           \
            const float* _q1 = img1 + imgbase + (size_t)((IY) * (W * 3)); \
            const float* _q2 = img2 + imgbase + (size_t)((IY) * (W * 3)); \
            A0 = _q1[colA]; A1 = _q1[colA + 1]; A2 = _q1[colA + 2];       \
            B0 = _q2[colA]; B1 = _q2[colA + 1]; B2 = _q2[colA + 2];       \
            if (halo) {                                                   \
                C0  = _q1[colB]; C1v = _q1[colB + 1]; C2v = _q1[colB + 2];\
                D0  = _q2[colB]; D1  = _q2[colB + 1]; D2  = _q2[colB + 2];\
            }                                                             \
        }                                                                 \
    }

// Convert current raw regs (row IY) to luma and store to LDS parity IY&1.
#define STORE_ROW(IY)                                                     \
    {                                                                     \
        const int _p = (IY) & 1;                                          \
        sbuf[_p][wvid][0][lane] = luma3(cA0, cA1, cA2);                   \
        sbuf[_p][wvid][1][lane] = luma3(cB0, cB1, cB2);                   \
        if (lane < 10) {                                                  \
            sbuf[_p][wvid][0][64 + lane] = luma3(cC0, cC1, cC2);          \
            sbuf[_p][wvid][1][64 + lane] = luma3(cD0, cD1, cD2);          \
        }                                                                 \
    }

#define ROTATE_RAW()                                                      \
    {                                                                     \
        cA0 = nA0; cA1 = nA1; cA2 = nA2; cB0 = nB0; cB1 = nB1; cB2 = nB2; \
        cC0 = nC0; cC1 = nC1; cC2 = nC2; cD0 = nD0; cD1 = nD1; cD2 = nD2; \
    }

// One row step (see header comment). NO barrier: LDS is wave-private.
#define ROW_STEP(IY, H0, H1, H2, H3)                                      \
    {                                                                     \
        LOAD_RAW((IY) + 2, nA0,nA1,nA2, nB0,nB1,nB2,                      \
                           nC0,nC1,nC2, nD0,nD1,nD2);                     \
        STORE_ROW((IY) + 1);                                              \
        ROTATE_RAW();                                                     \
        {                                                                 \
            const int _rb = (IY) & 1;                                     \
            float _h0 = 0.f, _h1 = 0.f, _h2 = 0.f, _h3 = 0.f;             \
            _Pragma("unroll")                                             \
            for (int _k = 0; _k < WS; ++_k) {                             \
                const float _gk = wv.g[_k];                               \
                const float _a = sbuf[_rb][wvid][0][lane + _k];           \
                const float _c = sbuf[_rb][wvid][1][lane + _k];           \
                _h0 += _gk * _a;                                          \
                _h1 += _gk * _c;                                          \
                _h2 += _gk * (_a * _a + _c * _c);                         \
                _h3 += _gk * (_a * _c);                                   \
            }                                                             \
            H0 = _h0; H1 = _h1; H2 = _h2; H3 = _h3;                       \
        }                                                                 \
    }

    // Register ring: slot s holds h-conv of input row r with r % 11 == s.
    float rm1[WS], rm2[WS], rq[WS], rx[WS];

    // Prologue: raw row 0 -> c; raw row 1 -> n (in flight); luma row 0 -> LDS.
    LOAD_RAW(0, cA0,cA1,cA2, cB0,cB1,cB2, cC0,cC1,cC2, cD0,cD1,cD2);
    LOAD_RAW(1, nA0,nA1,nA2, nB0,nB1,nB2, nC0,nC1,nC2, nD0,nD1,nD2);
    STORE_ROW(0);                       // one-time stall on row-0 loads
    ROTATE_RAW();                       // c = raw row 1

    // Fill ring with input rows 0..9 (slots 0..9).
    #pragma unroll
    for (int j = 0; j < 10; ++j)
        ROW_STEP(j, rm1[j], rm2[j], rq[j], rx[j]);

    double local = 0.0;

// Output row OY (JM == OY % 11, compile-time): insert row OY+10 at slot
// (JM+10)%11, then vertical 11-tap conv over slots (JM+k)%11 and SSIM.
#define DO_ROW(OY, JM)                                                    \
    {                                                                     \
        ROW_STEP((OY) + 10,                                               \
                 rm1[((JM) + 10) % WS], rm2[((JM) + 10) % WS],            \
                 rq[((JM) + 10) % WS],  rx[((JM) + 10) % WS]);            \
        float _mu1 = 0.f, _mu2 = 0.f, _eq = 0.f, _ex = 0.f;               \
        _Pragma("unroll")                                                 \
        for (int _k = 0; _k < WS; ++_k) {                                 \
            const float _gk = wv.g[_k];                                   \
            const int _s = ((JM) + _k) % WS;                              \
            _mu1 += _gk * rm1[_s];                                        \
            _mu2 += _gk * rm2[_s];                                        \
            _eq  += _gk * rq[_s];                                         \
            _ex  += _gk * rx[_s];                                         \
        }                                                                 \
        if (colok && (r0 + (OY)) < OUTD) {                                \
            const float _m1s = _mu1 * _mu1;                               \
            const float _m2s = _mu2 * _mu2;                               \
            const float _m12 = _mu1 * _mu2;                               \
            const float _num = (2.f * _m12 + C1F) *                       \
                               (2.f * (_ex - _m12) + C2F);                \
            const float _den = (_m1s + _m2s + C1F) *                      \
                               ((_eq - _m1s - _m2s) + C2F);               \
            local += (double)(_num / _den);                               \
        }                                                                 \
    }

    // Output rows 0..21 in two groups of 11 (base % 11 == 0 keeps slots
    // static); tail rows 22..31.
    for (int c = 0; c < 2; ++c) {
        const int base = c * 11;
        #pragma unroll
        for (int j = 0; j < 11; ++j)
            DO_ROW(base + j, j);
    }
    #pragma unroll
    for (int j = 0; j < 10; ++j)
        DO_ROW(22 + j, j);

    // Block reduction: wave shuffle -> LDS -> one atomic (only barrier).
    for (int off = 32; off > 0; off >>= 1)
        local += __shfl_down(local, off, 64);
    if (lane == 0) wsum[wvid] = local;
    __syncthreads();
    if (t == 0) {
        const double s = wsum[0] + wsum[1] + wsum[2] + wsum[3];
        atomicAdd(acc_out, s);
    }
}

__global__ void ssim_finalize_kernel(const double* __restrict__ acc,
                                     float* __restrict__ out)
{
    out[0] = (float)(acc[0] / N_OUT_TOTAL);
}

extern "C" void kernel_launch(void* const* d_in, const int* in_sizes, int n_in,
                              void* d_out, int out_size, void* d_ws, size_t ws_size,
                              hipStream_t stream) {
    const float* img1 = (const float*)d_in[0];
    const float* img2 = (const float*)d_in[1];
    float* out = (float*)d_out;
    double* acc = (double*)d_ws;

    // Gaussian window, computed exactly as the numpy reference (float32 ops)
    GW w;
    {
        float g[WS];
        float s = 0.f;
        for (int i = 0; i < WS; ++i) {
            const float x = (float)(i - WS / 2);
            g[i] = expf(-(x * x) / (2.f * 1.5f * 1.5f));
            s += g[i];
        }
        for (int i = 0; i < WS; ++i) w.g[i] = g[i] / s;
    }

    hipMemsetAsync(d_ws, 0, sizeof(double), stream);

    dim3 grid(2, (OUTD + STRIP - 1) / STRIP, BATCH);   // 2 x 16 x 32 = 1024 blocks
    ssim_stream_kernel<<<grid, 256, 0, stream>>>(img1, img2, acc, w);
    ssim_finalize_kernel<<<1, 1, 0, stream>>>(acc, out);
}

// Round 8
// 258.944 us; speedup vs baseline: 1.2033x; 1.0004x over previous
//
#include <hip/hip_runtime.h>
#include <math.h>

// Problem constants
#define BATCH 32
#define H 512
#define W 512
#define OUTD 502          // 512 - 11 + 1
#define WS 11
#define STRIP 32          // output rows per block
#define INROWS 42         // STRIP + WS - 1 input rows per strip
#define WPAD 80           // per-wave LDS row width: 64 cols + 10 halo + pad

#define C1F 6.5025f       // (0.01*255)^2
#define C2F 58.5225f      // (0.03*255)^2
#define N_OUT_TOTAL 8064128.0   // 32 * 502 * 502

struct GW { float g[WS]; };

__device__ __forceinline__ float luma3(float r, float g, float b) {
    r = (r + 1.f) * 127.5f; g = (g + 1.f) * 127.5f; b = (b + 1.f) * 127.5f;
    return (r * 65.738f + g * 129.057f + b * 25.064f) * (1.f / 256.f) + 16.f;
}

// Streaming SSIM, one thread per output column, 32-row strip per block,
// wave-private LDS (no barriers in the row loop).
// ROUND-8: rounds 6 & 7 (STRIP=33 + 3-chunk runtime loop) both FAILED
// (0.112 / NaN) despite provably-correct ring algebra — suspected
// undef-PHI miscompile of the partially-written ring under the rolled
// loop. This round: round-5 kernel VERBATIM (known-good, absmax 1.2e-4)
// plus exactly two deltas:
//   (a) zero-init ALL 11 ring slots (kills the undef class outright),
//   (b) `#pragma unroll 1` on the existing 2-chunk loop (minimal test of
//       the I$/re-roll hypothesis on otherwise-known-good code).
// Raw RGB loads stay software-pipelined one row ahead of first use
// (round-5); ring %11 indices compile-time; no pointers into register
// arrays (round-2 spill lesson).
__global__ __launch_bounds__(256) void ssim_stream_kernel(
    const float* __restrict__ img1, const float* __restrict__ img2,
    double* __restrict__ acc_out, GW wv)
{
    __shared__ float sbuf[2][4][2][WPAD];   // parity x wave x img x width
    __shared__ double wsum[4];

    const int t    = threadIdx.x;
    const int lane = t & 63;
    const int wvid = t >> 6;
    const int cw = blockIdx.x * 256 + wvid * 64;  // wave's first column
    const int ox = cw + lane;                     // owned output column
    const int r0 = blockIdx.y * STRIP;
    const int b  = blockIdx.z;

    const bool colok = (ox < OUTD);
    const bool halo  = (lane < 10) && ((cw + 64 + lane) < W);
    const size_t imgbase = (size_t)b * (H * W * 3) + (size_t)r0 * (W * 3);
    const int colA = (cw + lane) * 3;             // main col (always < W)
    const int colB = (cw + 64 + lane) * 3;        // halo col

    // Raw RGB pipeline registers: c* = row iy+1 (ready), n* = row iy+2 (in flight)
    float cA0, cA1, cA2, cB0, cB1, cB2, cC0, cC1, cC2, cD0, cD1, cD2;
    float nA0, nA1, nA2, nB0, nB1, nB2, nC0, nC1, nC2, nD0, nD1, nD2;

// Issue raw loads for strip row IY into 12 named registers (NO conversion
// here — keeping load->use distance at one full row step).
#define LOAD_RAW(IY, A0,A1,A2, B0,B1,B2, C0,C1v,C2v, D0,D1,D2)            \
    {                                                                     \
        A0=A1=A2=B0=B1=B2=C0=C1v=C2v=D0=D1=D2 = 0.f;                      \
        if ((IY) < INROWS && (r0 + (IY)) < H) {                           \
            const float* _q1 = img1 + imgbase + (size_t)((IY) * (W * 3)); \
            const float* _q2 = img2 + imgbase + (size_t)((IY) * (W * 3)); \
            A0 = _q1[colA]; A1 = _q1[colA + 1]; A2 = _q1[colA + 2];       \
            B0 = _q2[colA]; B1 = _q2[colA + 1]; B2 = _q2[colA + 2];       \
            if (halo) {                                                   \
                C0  = _q1[colB]; C1v = _q1[colB + 1]; C2v = _q1[colB + 2];\
                D0  = _q2[colB]; D1  = _q2[colB + 1]; D2  = _q2[colB + 2];\
            }                                                             \
        }                                                                 \
    }

// Convert current raw regs (row IY) to luma and store to LDS parity IY&1.
#define STORE_ROW(IY)                                                     \
    {                                                                     \
        const int _p = (IY) & 1;                                          \
        sbuf[_p][wvid][0][lane] = luma3(cA0, cA1, cA2);                   \
        sbuf[_p][wvid][1][lane] = luma3(cB0, cB1, cB2);                   \
        if (lane < 10) {                                                  \
            sbuf[_p][wvid][0][64 + lane] = luma3(cC0, cC1, cC2);          \
            sbuf[_p][wvid][1][64 + lane] = luma3(cD0, cD1, cD2);          \
        }                                                                 \
    }

#define ROTATE_RAW()                                                      \
    {                                                                     \
        cA0 = nA0; cA1 = nA1; cA2 = nA2; cB0 = nB0; cB1 = nB1; cB2 = nB2; \
        cC0 = nC0; cC1 = nC1; cC2 = nC2; cD0 = nD0; cD1 = nD1; cD2 = nD2; \
    }

// One row step: prefetch raw row IY+2; convert+store row IY+1; h-conv row
// IY from LDS into H0..H3. No barrier: LDS is wave-private.
#define ROW_STEP(IY, H0, H1, H2, H3)                                      \
    {                                                                     \
        LOAD_RAW((IY) + 2, nA0,nA1,nA2, nB0,nB1,nB2,                      \
                           nC0,nC1,nC2, nD0,nD1,nD2);                     \
        STORE_ROW((IY) + 1);                                              \
        ROTATE_RAW();                                                     \
        {                                                                 \
            const int _rb = (IY) & 1;                                     \
            float _h0 = 0.f, _h1 = 0.f, _h2 = 0.f, _h3 = 0.f;             \
            _Pragma("unroll")                                             \
            for (int _k = 0; _k < WS; ++_k) {                             \
                const float _gk = wv.g[_k];                               \
                const float _a = sbuf[_rb][wvid][0][lane + _k];           \
                const float _c = sbuf[_rb][wvid][1][lane + _k];           \
                _h0 += _gk * _a;                                          \
                _h1 += _gk * _c;                                          \
                _h2 += _gk * (_a * _a + _c * _c);                         \
                _h3 += _gk * (_a * _c);                                   \
            }                                                             \
            H0 = _h0; H1 = _h1; H2 = _h2; H3 = _h3;                       \
        }                                                                 \
    }

    // Register ring: slot s holds h-conv of input row r with r % 11 == s.
    // Zero-init ALL slots (incl. 10) — no undef values anywhere, ever.
    float rm1[WS], rm2[WS], rq[WS], rx[WS];
    #pragma unroll
    for (int s = 0; s < WS; ++s) {
        rm1[s] = 0.f; rm2[s] = 0.f; rq[s] = 0.f; rx[s] = 0.f;
    }

    // Prologue: raw row 0 -> c; raw row 1 -> n (in flight); luma row 0 -> LDS.
    LOAD_RAW(0, cA0,cA1,cA2, cB0,cB1,cB2, cC0,cC1,cC2, cD0,cD1,cD2);
    LOAD_RAW(1, nA0,nA1,nA2, nB0,nB1,nB2, nC0,nC1,nC2, nD0,nD1,nD2);
    STORE_ROW(0);                       // one-time stall on row-0 loads
    ROTATE_RAW();                       // c = raw row 1

    // Fill ring with input rows 0..9 (slots 0..9).
    #pragma unroll
    for (int j = 0; j < 10; ++j)
        ROW_STEP(j, rm1[j], rm2[j], rq[j], rx[j]);

    double local = 0.0;

// Output row OY (JM == OY % 11, compile-time): insert row OY+10 at slot
// (JM+10)%11, then vertical 11-tap conv over slots (JM+k)%11 and SSIM.
#define DO_ROW(OY, JM)                                                    \
    {                                                                     \
        ROW_STEP((OY) + 10,                                               \
                 rm1[((JM) + 10) % WS], rm2[((JM) + 10) % WS],            \
                 rq[((JM) + 10) % WS],  rx[((JM) + 10) % WS]);            \
        float _mu1 = 0.f, _mu2 = 0.f, _eq = 0.f, _ex = 0.f;               \
        _Pragma("unroll")                                                 \
        for (int _k = 0; _k < WS; ++_k) {                                 \
            const float _gk = wv.g[_k];                                   \
            const int _s = ((JM) + _k) % WS;                              \
            _mu1 += _gk * rm1[_s];                                        \
            _mu2 += _gk * rm2[_s];                                        \
            _eq  += _gk * rq[_s];                                         \
            _ex  += _gk * rx[_s];                                         \
        }                                                                 \
        if (colok && (r0 + (OY)) < OUTD) {                                \
            const float _m1s = _mu1 * _mu1;                               \
            const float _m2s = _mu2 * _mu2;                               \
            const float _m12 = _mu1 * _mu2;                               \
            const float _num = (2.f * _m12 + C1F) *                       \
                               (2.f * (_ex - _m12) + C2F);                \
            const float _den = (_m1s + _m2s + C1F) *                      \
                               ((_eq - _m1s - _m2s) + C2F);               \
            local += (double)(_num / _den);                               \
        }                                                                 \
    }

    // Output rows 0..21: 2-chunk loop, ROLLED (the round-8 experiment —
    // round 5 let the compiler unroll this); rows 22..31 unrolled tail.
    #pragma unroll 1
    for (int c = 0; c < 2; ++c) {
        const int base = c * 11;
        #pragma unroll
        for (int j = 0; j < 11; ++j)
            DO_ROW(base + j, j);
    }
    #pragma unroll
    for (int j = 0; j < 10; ++j)
        DO_ROW(22 + j, j);

    // Block reduction: wave shuffle -> LDS -> one atomic (only barrier).
    for (int off = 32; off > 0; off >>= 1)
        local += __shfl_down(local, off, 64);
    if (lane == 0) wsum[wvid] = local;
    __syncthreads();
    if (t == 0) {
        const double s = wsum[0] + wsum[1] + wsum[2] + wsum[3];
        atomicAdd(acc_out, s);
    }
}

__global__ void ssim_finalize_kernel(const double* __restrict__ acc,
                                     float* __restrict__ out)
{
    out[0] = (float)(acc[0] / N_OUT_TOTAL);
}

extern "C" void kernel_launch(void* const* d_in, const int* in_sizes, int n_in,
                              void* d_out, int out_size, void* d_ws, size_t ws_size,
                              hipStream_t stream) {
    const float* img1 = (const float*)d_in[0];
    const float* img2 = (const float*)d_in[1];
    float* out = (float*)d_out;
    double* acc = (double*)d_ws;

    // Gaussian window, computed exactly as the numpy reference (float32 ops)
    GW w;
    {
        float g[WS];
        float s = 0.f;
        for (int i = 0; i < WS; ++i) {
            const float x = (float)(i - WS / 2);
            g[i] = expf(-(x * x) / (2.f * 1.5f * 1.5f));
            s += g[i];
        }
        for (int i = 0; i < WS; ++i) w.g[i] = g[i] / s;
    }

    hipMemsetAsync(d_ws, 0, sizeof(double), stream);

    dim3 grid(2, (OUTD + STRIP - 1) / STRIP, BATCH);   // 2 x 16 x 32 = 1024 blocks
    ssim_stream_kernel<<<grid, 256, 0, stream>>>(img1, img2, acc, w);
    ssim_finalize_kernel<<<1, 1, 0, stream>>>(acc, out);
}